// Round 4
// baseline (22.051 us; speedup 1.0000x reference)
//
#include <hip/hip_runtime.h>

// Grouped batched matmul: y[t] = x[t] @ W[seg(t)] + b[seg(t)]
// x: [TOTAL, 32] f32, W: [N, 32, 32] f32, b: [N, 32] f32, cnt: [N] i32
//
// One wave per block, FOUR blocks per network (32 points each) -> 16 blocks/CU
// (4 waves/SIMD) for latency hiding. Flat vectorized prefix scan (int4 x 64
// lanes per pass, no dependent load loop). 4p x 4o register tile; all LDS
// access patterns broadcast or 2-way aliased (free).

#define NT 64
#define CHUNK 32
#define SPLIT 4

__global__ __launch_bounds__(NT) void mnl_kernel(
    const float* __restrict__ x,
    const float* __restrict__ w,
    const float* __restrict__ bias,
    const int* __restrict__ cnt,
    float* __restrict__ y)
{
    __shared__ float xT[32][CHUNK];  // 4 KB: transposed x chunk
    __shared__ float Wl[32][32];     // 4 KB: W row-major [in][out]

    const int b = blockIdx.x;
    const int n = b >> 2;            // network id
    const int q = b & 3;             // quarter of the segment
    const int t = threadIdx.x;

    // ---- issue W loads immediately (independent of everything) ----
    const float4* __restrict__ wg = reinterpret_cast<const float4*>(w + (size_t)n * 1024);
    const float4 wr0 = wg[t];
    const float4 wr1 = wg[t + 64];
    const float4 wr2 = wg[t + 128];
    const float4 wr3 = wg[t + 192];

    const int o0 = (t & 7) * 4;      // 4 consecutive outputs
    const int p0 = (t >> 3) * 4;     // 4 consecutive points

    const float4 b4 = *reinterpret_cast<const float4*>(bias + (size_t)n * 32 + o0);

    // ---- flat vectorized exclusive prefix sum: base = sum(cnt[0..n)) ----
    // int4 x 64 lanes = 256 counts per pass; independent loads, no dep chain.
    int s = 0;
    const int nf = n & ~3;
    const int4* __restrict__ c4 = reinterpret_cast<const int4*>(cnt);
    for (int j = 4 * t; j < nf; j += 4 * NT) {
        const int4 v = c4[j >> 2];
        s += v.x + v.y + v.z + v.w;
    }
    for (int j = nf + t; j < n; j += NT) s += cnt[j];
    #pragma unroll
    for (int off = 32; off > 0; off >>= 1) s += __shfl_xor(s, off, 64);
    const int base  = s;
    const int count = cnt[n];

    // ---- stage W into LDS (consecutive b128 writes, conflict-free) ----
    {
        float4* wl4 = reinterpret_cast<float4*>(&Wl[0][0]);
        wl4[t]       = wr0;
        wl4[t + 64]  = wr1;
        wl4[t + 128] = wr2;
        wl4[t + 192] = wr3;
    }

    const int pr = t >> 1;           // row this lane stages (0..31)
    const int cg = (t & 1) * 4;      // starting float4 col-group (0 or 4)

    for (int pc = q * CHUNK; pc < count; pc += SPLIT * CHUNK) {
        // ---- load: 2 lanes per row, 64B each, fully coalesced ----
        float4 rr[4];
        const int pg = pc + pr;
        if (pg < count) {
            const float4* __restrict__ xg =
                reinterpret_cast<const float4*>(x + (size_t)(base + pg) * 32);
            #pragma unroll
            for (int k = 0; k < 4; ++k) rr[k] = xg[cg + k];
        } else {
            #pragma unroll
            for (int k = 0; k < 4; ++k) rr[k] = make_float4(0.f, 0.f, 0.f, 0.f);
        }

        __syncthreads();  // 1-wave barrier: prev iter xT reads done / W staged

        // ---- transposed write: bank = pr, 2 lanes/bank (free) ----
        #pragma unroll
        for (int k = 0; k < 4; ++k) {
            const int c = cg + k;
            xT[4 * c + 0][pr] = rr[k].x;
            xT[4 * c + 1][pr] = rr[k].y;
            xT[4 * c + 2][pr] = rr[k].z;
            xT[4 * c + 3][pr] = rr[k].w;
        }

        __syncthreads();  // 1-wave barrier

        // ---- compute: 4p x 4o register tile, acc seeded with bias ----
        float4 acc[4];
        #pragma unroll
        for (int pp = 0; pp < 4; ++pp) acc[pp] = b4;

        #pragma unroll
        for (int i = 0; i < 32; ++i) {
            const float4 xv = *reinterpret_cast<const float4*>(&xT[i][p0]);
            const float4 wv = *reinterpret_cast<const float4*>(&Wl[i][o0]);
            const float xs[4] = {xv.x, xv.y, xv.z, xv.w};
            #pragma unroll
            for (int pp = 0; pp < 4; ++pp) {
                acc[pp].x = fmaf(xs[pp], wv.x, acc[pp].x);
                acc[pp].y = fmaf(xs[pp], wv.y, acc[pp].y);
                acc[pp].z = fmaf(xs[pp], wv.z, acc[pp].z);
                acc[pp].w = fmaf(xs[pp], wv.w, acc[pp].w);
            }
        }

        // ---- store: coalesced float4 ----
        #pragma unroll
        for (int pp = 0; pp < 4; ++pp) {
            const int prow = pc + p0 + pp;
            if (prow < count)
                *reinterpret_cast<float4*>(&y[(size_t)(base + prow) * 32 + o0]) = acc[pp];
        }
    }
}

extern "C" void kernel_launch(void* const* d_in, const int* in_sizes, int n_in,
                              void* d_out, int out_size, void* d_ws, size_t ws_size,
                              hipStream_t stream) {
    const float* x    = (const float*)d_in[0];
    const float* w    = (const float*)d_in[1];
    const float* bias = (const float*)d_in[2];
    const int*   cnt  = (const int*)d_in[3];
    float*       y    = (float*)d_out;
    const int n_nets  = in_sizes[3];

    mnl_kernel<<<SPLIT * n_nets, NT, 0, stream>>>(x, w, bias, cnt, y);
}

// Round 5
// 18.424 us; speedup vs baseline: 1.1969x; 1.1969x over previous
//
#include <hip/hip_runtime.h>

// Grouped batched matmul: y[t] = x[t] @ W[seg(t)] + b[seg(t)]
// x: [TOTAL, 32] f32, W: [N, 32, 32] f32, b: [N, 32] f32, cnt: [N] i32
//
// Minimal-critical-path variant: one network per block, 128 threads,
// ONE POINT PER THREAD. x row lives in 32 VGPRs (no LDS transpose).
// W + bias staged once into LDS and read as uniform-address float4
// broadcasts (conflict-free by definition). Per-wave independent prefix
// scan so x loads issue before the single barrier.

#define NT 128

__global__ __launch_bounds__(NT) void mnl_kernel(
    const float* __restrict__ x,
    const float* __restrict__ w,
    const float* __restrict__ bias,
    const int* __restrict__ cnt,
    float* __restrict__ y)
{
    __shared__ float Wl[32 * 32];   // 4 KB, row-major [in][out]
    __shared__ float Bl[32];

    const int n = blockIdx.x;
    const int t = threadIdx.x;
    const int l = t & 63;           // lane within wave

    // ---- per-wave flat scan of cnt[0..n): int4 x 64 lanes, no barriers ----
    int s = 0;
    {
        const int4* __restrict__ c4 = reinterpret_cast<const int4*>(cnt);
        const int ng = n >> 2;                       // full int4 groups
        for (int g = l; g < ng; g += 64) {
            const int4 v = c4[g];
            s += v.x + v.y + v.z + v.w;
        }
        for (int j = (ng << 2) + l; j < n; j += 64) s += cnt[j];
    }

    // ---- W / bias global loads (independent; in flight during scan) ----
    const float4* __restrict__ wg = reinterpret_cast<const float4*>(w + (size_t)n * 1024);
    const float4 wr0 = wg[t];
    const float4 wr1 = wg[t + NT];
    float4 br;
    if (t < 8) br = reinterpret_cast<const float4*>(bias + (size_t)n * 32)[t];

    const int count = cnt[n];

    // ---- wave reduce -> base (no cross-wave combine needed) ----
    #pragma unroll
    for (int off = 32; off > 0; off >>= 1) s += __shfl_xor(s, off, 64);
    const int base = s;

    // ---- issue x row loads immediately (before barrier) ----
    float4 xr[8];
    const bool live = t < count;
    if (live) {
        const float4* __restrict__ xg =
            reinterpret_cast<const float4*>(x + (size_t)(base + t) * 32);
        #pragma unroll
        for (int k = 0; k < 8; ++k) xr[k] = xg[k];
    }

    // ---- stage W + bias into LDS; single barrier ----
    {
        float4* wl4 = reinterpret_cast<float4*>(Wl);
        wl4[t]      = wr0;
        wl4[t + NT] = wr1;
        if (t < 8) reinterpret_cast<float4*>(Bl)[t] = br;
    }
    __syncthreads();

    // ---- compute: acc[32] seeded with bias (broadcast reads) ----
    float4 acc[8];
    #pragma unroll
    for (int g = 0; g < 8; ++g)
        acc[g] = *reinterpret_cast<const float4*>(&Bl[4 * g]);

    float xv[32];
    #pragma unroll
    for (int k = 0; k < 8; ++k) {
        xv[4 * k + 0] = xr[k].x;
        xv[4 * k + 1] = xr[k].y;
        xv[4 * k + 2] = xr[k].z;
        xv[4 * k + 3] = xr[k].w;
    }

    const float4* __restrict__ wl4 = reinterpret_cast<const float4*>(Wl);
    #pragma unroll
    for (int i = 0; i < 32; ++i) {
        const float xi = xv[i];
        #pragma unroll
        for (int g = 0; g < 8; ++g) {
            const float4 wv = wl4[8 * i + g];   // uniform address -> broadcast
            acc[g].x = fmaf(xi, wv.x, acc[g].x);
            acc[g].y = fmaf(xi, wv.y, acc[g].y);
            acc[g].z = fmaf(xi, wv.z, acc[g].z);
            acc[g].w = fmaf(xi, wv.w, acc[g].w);
        }
    }

    // ---- store full y row (8 x dwordx4) ----
    if (live) {
        float4* __restrict__ yr =
            reinterpret_cast<float4*>(y + (size_t)(base + t) * 32);
        #pragma unroll
        for (int g = 0; g < 8; ++g) yr[g] = acc[g];
    }
}

extern "C" void kernel_launch(void* const* d_in, const int* in_sizes, int n_in,
                              void* d_out, int out_size, void* d_ws, size_t ws_size,
                              hipStream_t stream) {
    const float* x    = (const float*)d_in[0];
    const float* w    = (const float*)d_in[1];
    const float* bias = (const float*)d_in[2];
    const int*   cnt  = (const int*)d_in[3];
    float*       y    = (float*)d_out;
    const int n_nets  = in_sizes[3];

    mnl_kernel<<<n_nets, NT, 0, stream>>>(x, w, bias, cnt, y);
}